// Round 11
// baseline (1077.514 us; speedup 1.0000x reference)
//
#include <hip/hip_runtime.h>

// VQ-VAE Vector Quantizer: N=65536 rows, K=4096 codes, D=64, fp32.
// R12: R10 + sched_barrier-pinned refills. R11 (2-row retry) hit its
// pre-registered failure exactly (VGPR capped at 128 + 23MB scratch despite
// waves_per_eu(2)) -> 2-row branch closed permanently. R10 accounting:
// ~100 VALU instr/code issued vs 74 algorithmic. Hypothesis: WAR-renaming
// copies — the scheduler hoists refill loads above the consuming FMAs by
// v_mov-ing the bank into temps (~26-32 movs/code), a good trade when
// refills were L2 (~250cy) but pure waste now that R10's warming makes them
// L1 hits (~50cy). Fix: __builtin_amdgcn_sched_barrier(0) between each
// phase's FMAs and its refill loads (2/iter) — loads pinned after consumers,
// copies have no purpose, compiler still manages all vmcnt waits (safe).
// Next-iter consumption slack ~400cy >> L1 latency -> no new stall.
// Data path byte-identical to R10. FMA sequence per (row,code) bit-identical
// to R0/R7/R9/R10 passing kernels (quad-split partials by d mod 4, ascending
// d, (s0+s1)+(s2+s3), dist = (z2 + e2[k]) - 2*dot, strict < first-index
// tie-break) => identical indices, absmax 0 by construction.
//
// out layout (float): [0,N*D) z_q_st | [ND] vq | [ND+1] cb | [ND+2] cm |
//                     [ND+3, ND+3+N) indices | [ND+3+N] perplexity | [ND+4+N] active

constexpr int N = 65536;
constexpr int K = 4096;
constexpr int D = 64;
constexpr int S = 8;      // K-split: grid = 2048 blocks
constexpr int KS = K / S; // 512 codes per slice
constexpr int SLICE_BYTES = KS * D * 4;        // 131072
constexpr int WARM_AHEAD = 2048;               // 8 codes ahead
constexpr int WARM_WRAP = SLICE_BYTES - 1024;  // keep +tid*4 in-slice

__global__ __launch_bounds__(256) void prep_kernel(const float* __restrict__ emb,
                                                   float* __restrict__ e2,
                                                   int* __restrict__ counts,
                                                   float* __restrict__ loss) {
  int k = blockIdx.x * 256 + threadIdx.x;
  if (k < K) {
    const float4* ep = (const float4*)(emb + (size_t)k * D);
    float s0 = 0.f, s1 = 0.f, s2 = 0.f, s3 = 0.f;
#pragma unroll
    for (int i = 0; i < 16; ++i) {
      float4 e = ep[i];
      s0 = fmaf(e.x, e.x, s0);
      s1 = fmaf(e.y, e.y, s1);
      s2 = fmaf(e.z, e.z, s2);
      s3 = fmaf(e.w, e.w, s3);
    }
    e2[k] = (s0 + s1) + (s2 + s3);
    counts[k] = 0;
  }
  if (blockIdx.x == 0 && threadIdx.x == 0) *loss = 0.0f;
}

// Scan one K-slice for 256 rows per block. grid = (N/256, S). No LDS.
__global__ __launch_bounds__(256) void vq_scan(const float* __restrict__ z,
                                               const float* __restrict__ emb,
                                               const float* __restrict__ e2,
                                               float* __restrict__ pbest,
                                               int* __restrict__ pidx) {
  const int tid = threadIdx.x;
  const int n = blockIdx.x * 256 + tid;
  const int s = blockIdx.y;
  const int k0 = s * KS;

  // This lane's z row (register-resident on the unified file).
  float4 zr[16];
  {
    const float4* zp = (const float4*)(z + (size_t)n * D);
#pragma unroll
    for (int i = 0; i < 16; ++i) zr[i] = zp[i];
  }

  // z2, same instruction sequence as R0/R10 (quad-split by d mod 4, ascending d).
  float z2;
  {
    float s0 = 0.f, s1 = 0.f, s2 = 0.f, s3 = 0.f;
#pragma unroll
    for (int i = 0; i < 16; ++i) {
      s0 = fmaf(zr[i].x, zr[i].x, s0);
      s1 = fmaf(zr[i].y, zr[i].y, s1);
      s2 = fmaf(zr[i].z, zr[i].z, s2);
      s3 = fmaf(zr[i].w, zr[i].w, s3);
    }
    z2 = (s0 + s1) + (s2 + s3);
  }

  // Uniform slice base (SGPR) + running pointers; body loads use imm offsets.
  const char* sb = (const char*)(emb + (size_t)k0 * D);
  const float4* fc = (const float4*)sb;  // current code
  const float* e2c = e2 + k0;
  const int lane4 = tid * 4;             // per-lane warm offset
  float warm = 0.0f;                     // warm-load dummy dest

  // Prologue: preload code 0 into the two banks (f=0..7 -> rr, f=8..15 -> qq).
  float4 rr[8], qq[8];
#pragma unroll
  for (int j = 0; j < 8; ++j) rr[j] = fc[j];
#pragma unroll
  for (int j = 0; j < 8; ++j) qq[j] = fc[8 + j];
  float e2cur = e2c[0];

  float best = 3.4e38f;
  int bidx = k0;

  for (int k = 0; k < KS - 1; ++k) {
    float s0 = 0.f, s1 = 0.f, s2 = 0.f, s3 = 0.f;
    // Phase 1: consume rr (f=0..7 of code k).
#pragma unroll
    for (int j = 0; j < 8; ++j) {
      float4 e = rr[j];
      // d = 4*j + {0,1,2,3}; partial sN takes d%4==N, ascending d
      s0 = fmaf(zr[j].x, e.x, s0);
      s1 = fmaf(zr[j].y, e.y, s1);
      s2 = fmaf(zr[j].z, e.z, s2);
      s3 = fmaf(zr[j].w, e.w, s3);
    }
    // Pin the refills AFTER the consuming FMAs: no WAR-renaming copies.
    __builtin_amdgcn_sched_barrier(0);
#pragma unroll
    for (int j = 0; j < 8; ++j) rr[j] = fc[16 + j];  // imm offset 256+16j
    float e2n = e2c[1];
    // Phase 2: consume qq (f=8..15 of code k).
#pragma unroll
    for (int j = 0; j < 8; ++j) {
      float4 e = qq[j];
      s0 = fmaf(zr[8 + j].x, e.x, s0);
      s1 = fmaf(zr[8 + j].y, e.y, s1);
      s2 = fmaf(zr[8 + j].z, e.z, s2);
      s3 = fmaf(zr[8 + j].w, e.w, s3);
    }
    __builtin_amdgcn_sched_barrier(0);
#pragma unroll
    for (int j = 0; j < 8; ++j) qq[j] = fc[24 + j];  // imm offset 384+16j

    float dot = (s0 + s1) + (s2 + s3);
    float dist = (z2 + e2cur) - 2.0f * dot;  // reference fp32 rounding replicated
    if (dist < best) { best = dist; bidx = k0 + k; }  // strict <: first-index in slice
    e2cur = e2n;

    // L1-warming prefetch, 8 codes ahead, wrapped within the slice (uniform
    // SALU). Sink the PREVIOUS warm value, then overwrite with the new load.
    {
      int uoff = k * 256 + WARM_AHEAD;
      uoff = (uoff >= WARM_WRAP) ? (uoff - WARM_WRAP) : uoff;
      asm volatile("" :: "v"(warm));
      warm = *(const float*)(sb + uoff + lane4);
    }

    fc += 16;
    e2c += 1;
  }
  {
    // Final code (k = KS-1): identical FMA sequence, no refill, no warm.
    float s0 = 0.f, s1 = 0.f, s2 = 0.f, s3 = 0.f;
#pragma unroll
    for (int j = 0; j < 8; ++j) {
      float4 e = rr[j];
      s0 = fmaf(zr[j].x, e.x, s0);
      s1 = fmaf(zr[j].y, e.y, s1);
      s2 = fmaf(zr[j].z, e.z, s2);
      s3 = fmaf(zr[j].w, e.w, s3);
    }
#pragma unroll
    for (int j = 0; j < 8; ++j) {
      float4 e = qq[j];
      s0 = fmaf(zr[8 + j].x, e.x, s0);
      s1 = fmaf(zr[8 + j].y, e.y, s1);
      s2 = fmaf(zr[8 + j].z, e.z, s2);
      s3 = fmaf(zr[8 + j].w, e.w, s3);
    }
    float dot = (s0 + s1) + (s2 + s3);
    float dist = (z2 + e2cur) - 2.0f * dot;
    if (dist < best) { best = dist; bidx = k0 + KS - 1; }
    asm volatile("" :: "v"(warm));  // keep the last warm load alive
  }

  pbest[(size_t)s * N + n] = best;
  pidx[(size_t)s * N + n] = bidx;
}

// Combine slices (ascending s = ascending k => first-index tie-break preserved),
// then gather/losses/counts/index write.
__global__ __launch_bounds__(256) void vq_epilogue(const float* __restrict__ z,
                                                   const float* __restrict__ emb,
                                                   const float* __restrict__ pbest,
                                                   const int* __restrict__ pidx,
                                                   float* __restrict__ out,
                                                   int* __restrict__ counts,
                                                   float* __restrict__ loss) {
  __shared__ float red[4];
  const int tid = threadIdx.x;
  const int n = blockIdx.x * 256 + tid;

  float best = pbest[n];
  int bidx = pidx[n];
#pragma unroll
  for (int s = 1; s < S; ++s) {
    float d = pbest[(size_t)s * N + n];
    if (d < best) { best = d; bidx = pidx[(size_t)s * N + n]; }
  }

  out[(size_t)N * D + 3 + n] = (float)bidx;
  atomicAdd(&counts[bidx], 1);

  const float4* zp = (const float4*)(z + (size_t)n * D);
  const float4* qp = (const float4*)(emb + (size_t)bidx * D);
  float4* op = (float4*)(out + (size_t)n * D);
  float lsum = 0.f;
#pragma unroll
  for (int i = 0; i < 16; ++i) {
    float4 q = qp[i];
    float4 zz = zp[i];
    float dx = q.x - zz.x, dy = q.y - zz.y, dz = q.z - zz.z, dw = q.w - zz.w;
    lsum = fmaf(dx, dx, lsum);
    lsum = fmaf(dy, dy, lsum);
    lsum = fmaf(dz, dz, lsum);
    lsum = fmaf(dw, dw, lsum);
    // z_q_st = z + (z_q - z), replicated op-for-op
    float4 r;
    r.x = zz.x + dx; r.y = zz.y + dy; r.z = zz.z + dz; r.w = zz.w + dw;
    op[i] = r;
  }

#pragma unroll
  for (int off = 32; off > 0; off >>= 1) lsum += __shfl_down(lsum, off);
  if ((tid & 63) == 0) red[tid >> 6] = lsum;
  __syncthreads();
  if (tid == 0) atomicAdd(loss, (red[0] + red[1]) + (red[2] + red[3]));
}

__global__ __launch_bounds__(256) void finalize_kernel(const int* __restrict__ counts,
                                                       const float* __restrict__ loss,
                                                       float* __restrict__ out) {
  const int tid = threadIdx.x;
  double ent = 0.0;
  int active = 0;
  for (int k = tid; k < K; k += 256) {
    int c = counts[k];
    float p = (float)c / 65536.0f;
    if (c > 0) active++;
    ent += (double)(p * logf(p + 1e-10f));
  }
#pragma unroll
  for (int off = 32; off > 0; off >>= 1) {
    ent += __shfl_down(ent, off);
    active += __shfl_down(active, off);
  }
  __shared__ double ered[4];
  __shared__ int ared[4];
  if ((tid & 63) == 0) { ered[tid >> 6] = ent; ared[tid >> 6] = active; }
  __syncthreads();
  if (tid == 0) {
    double e = (ered[0] + ered[1]) + (ered[2] + ered[3]);
    int a = (ared[0] + ared[1]) + (ared[2] + ared[3]);
    float mean = *loss / (float)((size_t)N * D);
    float cb = mean;
    float cm = mean;
    float vq = cb + 0.25f * cm;
    size_t base = (size_t)N * D;
    out[base + 0] = vq;
    out[base + 1] = cb;
    out[base + 2] = cm;
    out[base + 3 + N] = (float)exp(-e);
    out[base + 4 + N] = (float)a;
  }
}

extern "C" void kernel_launch(void* const* d_in, const int* in_sizes, int n_in,
                              void* d_out, int out_size, void* d_ws, size_t ws_size,
                              hipStream_t stream) {
  const float* z = (const float*)d_in[0];
  const float* emb = (const float*)d_in[1];
  float* out = (float*)d_out;

  char* w = (char*)d_ws;
  float* e2 = (float*)w;                         w += (size_t)K * sizeof(float);
  int* counts = (int*)w;                         w += (size_t)K * sizeof(int);
  float* loss = (float*)w;                       w += 256;  // keep alignment
  float* pbest = (float*)w;                      w += (size_t)S * N * sizeof(float);
  int* pidx = (int*)w;

  prep_kernel<<<K / 256, 256, 0, stream>>>(emb, e2, counts, loss);
  vq_scan<<<dim3(N / 256, S), 256, 0, stream>>>(z, emb, e2, pbest, pidx);
  vq_epilogue<<<N / 256, 256, 0, stream>>>(z, emb, pbest, pidx, out, counts, loss);
  finalize_kernel<<<1, 256, 0, stream>>>(counts, loss, out);
}

// Round 14
// 634.786 us; speedup vs baseline: 1.6974x; 1.6974x over previous
//
#include <hip/hip_runtime.h>

// VQ-VAE Vector Quantizer: N=65536 rows, K=4096 codes, D=64, fp32.
// R13 (2nd resubmit — rounds 12 and 13 were broker timeouts, kernel has
// never run): MFMA two-pass rewrite. The VALU path is exhausted (R10 483us
// best; allocator caps 128 VGPR (R8/R11), sched pinning destructive (R12)).
// dist = z2 + e2 - 2*(z @ e^T) is a GEMM -> use mfma_f32_16x16x32_bf16 with
// bf16x2 error-free-product split (zh,zl)x(eh,el), 6 products/k64 (drop ll,
// residual ~1.5e-8 + mfma accum rounding ~2e-7 << band).
// Pass 1: approx dist sweep -> per-row amin (no indices).
// Pass 2: identical approx sweep; codes with d <= amin+1e-4 (provably
// includes the exact winner: |approx-exactf32| <= ~1.3e-5) get the BIT-EXACT
// R10 fp32 dist recompute (same quad-split FMA sequence, same z2/e2 values)
// and a lexicographic atomicMin on packed (dist_bits<<32|code) -> exact
// first-index argmin semantics, indices identical to R10 by construction.
// Layout: C/D col=lane&15, row=(lane>>4)*4+reg [HW-verified m89/m91]. A/B
// frag k-order ambiguity cancels: both operands packed with the SAME
// (lane>>4, elem)->k convention (k = 32c + 8g + j), and dot products are
// permutation-invariant in k.
//
// out layout (float): [0,N*D) z_q_st | [ND] vq | [ND+1] cb | [ND+2] cm |
//                     [ND+3, ND+3+N) indices | [ND+3+N] perplexity | [ND+4+N] active

constexpr int N = 65536;
constexpr int K = 4096;
constexpr int D = 64;

typedef short s8v __attribute__((ext_vector_type(8)));   // 8 bf16 (4 VGPRs)
typedef float f4 __attribute__((ext_vector_type(4)));    // 4 fp32 acc

#define MFMA(a, b, c) __builtin_amdgcn_mfma_f32_16x16x32_bf16((a), (b), (c), 0, 0, 0)

__device__ inline unsigned bfr(float x) {  // fp32 -> bf16 bits, RNE
  unsigned b = __float_as_uint(x);
  return (b + 0x7FFFu + ((b >> 16) & 1u)) >> 16;
}

__device__ inline void splitbf(const float4 v0, const float4 v1, s8v& hi, s8v& lo) {
  float x[8] = {v0.x, v0.y, v0.z, v0.w, v1.x, v1.y, v1.z, v1.w};
#pragma unroll
  for (int j = 0; j < 8; ++j) {
    unsigned h = bfr(x[j]);
    float hf = __uint_as_float(h << 16);
    unsigned l = bfr(x[j] - hf);
    hi[j] = (short)h;
    lo[j] = (short)l;
  }
}

// prep: e2 (exact quad-split, same as R10), counts=0, loss=0, bf16x2 split of emb.
__global__ __launch_bounds__(256) void prep_emb(const float* __restrict__ emb,
                                                float* __restrict__ e2,
                                                int* __restrict__ counts,
                                                float* __restrict__ loss,
                                                unsigned short* __restrict__ eh,
                                                unsigned short* __restrict__ el) {
  int k = blockIdx.x * 256 + threadIdx.x;
  if (k < K) {
    const float4* ep = (const float4*)(emb + (size_t)k * D);
    unsigned short* ehr = eh + (size_t)k * D;
    unsigned short* elr = el + (size_t)k * D;
    float s0 = 0.f, s1 = 0.f, s2 = 0.f, s3 = 0.f;
#pragma unroll
    for (int i = 0; i < 16; ++i) {
      float4 e = ep[i];
      s0 = fmaf(e.x, e.x, s0);
      s1 = fmaf(e.y, e.y, s1);
      s2 = fmaf(e.z, e.z, s2);
      s3 = fmaf(e.w, e.w, s3);
      float xs[4] = {e.x, e.y, e.z, e.w};
#pragma unroll
      for (int c = 0; c < 4; ++c) {
        unsigned h = bfr(xs[c]);
        ehr[4 * i + c] = (unsigned short)h;
        elr[4 * i + c] = (unsigned short)bfr(xs[c] - __uint_as_float(h << 16));
      }
    }
    e2[k] = (s0 + s1) + (s2 + s3);
    counts[k] = 0;
  }
  if (blockIdx.x == 0 && threadIdx.x == 0) *loss = 0.0f;
}

// prep: z2 per row (exact quad-split, bit-identical to R10's in-kernel z2) + cand init.
__global__ __launch_bounds__(256) void prep_z(const float* __restrict__ z,
                                              float* __restrict__ z2,
                                              unsigned long long* __restrict__ cand) {
  int n = blockIdx.x * 256 + threadIdx.x;
  const float4* zp = (const float4*)(z + (size_t)n * D);
  float s0 = 0.f, s1 = 0.f, s2 = 0.f, s3 = 0.f;
#pragma unroll
  for (int i = 0; i < 16; ++i) {
    float4 v = zp[i];
    s0 = fmaf(v.x, v.x, s0);
    s1 = fmaf(v.y, v.y, s1);
    s2 = fmaf(v.z, v.z, s2);
    s3 = fmaf(v.w, v.w, s3);
  }
  z2[n] = (s0 + s1) + (s2 + s3);
  cand[n] = 0x7F800000FFFFFFFFull;  // (+inf bits, idx max)
}

// Pass 1: approx dist sweep via MFMA; per-row min written to amin.
// Block = 4 waves; wave owns 2 row-tiles (32 rows); grid = N/128 = 512.
__global__ __launch_bounds__(256) void sweep1(const float* __restrict__ z,
                                              const float* __restrict__ z2g,
                                              const float* __restrict__ e2,
                                              const unsigned short* __restrict__ eh,
                                              const unsigned short* __restrict__ el,
                                              float* __restrict__ amin) {
  const int tid = threadIdx.x;
  const int lane = tid & 63;
  const int wv = tid >> 6;
  const int g = lane >> 4;
  const int c15 = lane & 15;
  const int rowbase = blockIdx.x * 128 + wv * 32;

  // A fragments: z rows (lane&15 selects row), k = 32c + 8g + j, bf16x2 split.
  s8v Ah[2][2], Al[2][2];
#pragma unroll
  for (int rt = 0; rt < 2; ++rt) {
    const float* zrow = z + (size_t)(rowbase + rt * 16 + c15) * D;
#pragma unroll
    for (int c = 0; c < 2; ++c) {
      float4 v0 = *(const float4*)(zrow + c * 32 + g * 8);
      float4 v1 = *(const float4*)(zrow + c * 32 + g * 8 + 4);
      splitbf(v0, v1, Ah[rt][c], Al[rt][c]);
    }
  }
  // z2 for the rows this lane's acc covers: row = rowbase + rt*16 + g*4 + r.
  float z2r[2][4];
#pragma unroll
  for (int rt = 0; rt < 2; ++rt)
#pragma unroll
    for (int r = 0; r < 4; ++r) z2r[rt][r] = z2g[rowbase + rt * 16 + g * 4 + r];

  const char* ehb = (const char*)eh;
  const char* elb = (const char*)el;
  unsigned boff = (unsigned)(c15 * 128 + g * 16);  // code row (col) + k-chunk offset
  const float* e2p = e2 + c15;

  float best[2][4];
#pragma unroll
  for (int rt = 0; rt < 2; ++rt)
#pragma unroll
    for (int r = 0; r < 4; ++r) best[rt][r] = 3.4e38f;

  for (int t = 0; t < K / 16; ++t) {
    s8v bh0 = *(const s8v*)(ehb + boff);
    s8v bh1 = *(const s8v*)(ehb + boff + 64);
    s8v bl0 = *(const s8v*)(elb + boff);
    s8v bl1 = *(const s8v*)(elb + boff + 64);
    float e2v = *e2p;
#pragma unroll
    for (int rt = 0; rt < 2; ++rt) {
      f4 acc = {0.f, 0.f, 0.f, 0.f};
      acc = MFMA(Ah[rt][0], bh0, acc);
      acc = MFMA(Ah[rt][1], bh1, acc);
      acc = MFMA(Al[rt][0], bh0, acc);
      acc = MFMA(Al[rt][1], bh1, acc);
      acc = MFMA(Ah[rt][0], bl0, acc);
      acc = MFMA(Ah[rt][1], bl1, acc);
#pragma unroll
      for (int r = 0; r < 4; ++r) {
        float d = (z2r[rt][r] + e2v) - 2.0f * acc[r];
        best[rt][r] = fminf(best[rt][r], d);
      }
    }
    boff += 2048;  // 16 codes * 128B
    e2p += 16;
  }

  // Cross-lane min within each 16-lane group (rows are group-local).
#pragma unroll
  for (int m = 1; m < 16; m <<= 1) {
#pragma unroll
    for (int rt = 0; rt < 2; ++rt)
#pragma unroll
      for (int r = 0; r < 4; ++r)
        best[rt][r] = fminf(best[rt][r], __shfl_xor(best[rt][r], m));
  }
  if (c15 == 0) {
#pragma unroll
    for (int rt = 0; rt < 2; ++rt)
#pragma unroll
      for (int r = 0; r < 4; ++r)
        amin[rowbase + rt * 16 + g * 4 + r] = best[rt][r];
  }
}

// Pass 2: identical approx sweep; candidates within band get the BIT-EXACT
// R10 fp32 dist and a lexicographic atomicMin on (dist_bits<<32 | code).
__global__ __launch_bounds__(256) void sweep2(const float* __restrict__ z,
                                              const float* __restrict__ emb,
                                              const float* __restrict__ z2g,
                                              const float* __restrict__ e2,
                                              const unsigned short* __restrict__ eh,
                                              const unsigned short* __restrict__ el,
                                              const float* __restrict__ amin,
                                              unsigned long long* __restrict__ cand) {
  const int tid = threadIdx.x;
  const int lane = tid & 63;
  const int wv = tid >> 6;
  const int g = lane >> 4;
  const int c15 = lane & 15;
  const int rowbase = blockIdx.x * 128 + wv * 32;

  s8v Ah[2][2], Al[2][2];
#pragma unroll
  for (int rt = 0; rt < 2; ++rt) {
    const float* zrow = z + (size_t)(rowbase + rt * 16 + c15) * D;
#pragma unroll
    for (int c = 0; c < 2; ++c) {
      float4 v0 = *(const float4*)(zrow + c * 32 + g * 8);
      float4 v1 = *(const float4*)(zrow + c * 32 + g * 8 + 4);
      splitbf(v0, v1, Ah[rt][c], Al[rt][c]);
    }
  }
  float z2r[2][4], aband[2][4];
#pragma unroll
  for (int rt = 0; rt < 2; ++rt)
#pragma unroll
    for (int r = 0; r < 4; ++r) {
      int row = rowbase + rt * 16 + g * 4 + r;
      z2r[rt][r] = z2g[row];
      aband[rt][r] = amin[row] + 1e-4f;  // band >> (approx err + fp32-path err)
    }

  const char* ehb = (const char*)eh;
  const char* elb = (const char*)el;
  unsigned boff = (unsigned)(c15 * 128 + g * 16);
  const float* e2p = e2 + c15;

  for (int t = 0; t < K / 16; ++t) {
    s8v bh0 = *(const s8v*)(ehb + boff);
    s8v bh1 = *(const s8v*)(ehb + boff + 64);
    s8v bl0 = *(const s8v*)(elb + boff);
    s8v bl1 = *(const s8v*)(elb + boff + 64);
    float e2v = *e2p;
#pragma unroll
    for (int rt = 0; rt < 2; ++rt) {
      f4 acc = {0.f, 0.f, 0.f, 0.f};
      acc = MFMA(Ah[rt][0], bh0, acc);
      acc = MFMA(Ah[rt][1], bh1, acc);
      acc = MFMA(Al[rt][0], bh0, acc);
      acc = MFMA(Al[rt][1], bh1, acc);
      acc = MFMA(Ah[rt][0], bl0, acc);
      acc = MFMA(Ah[rt][1], bl1, acc);
#pragma unroll
      for (int r = 0; r < 4; ++r) {
        float d = (z2r[rt][r] + e2v) - 2.0f * acc[r];
        if (d <= aband[rt][r]) {
          // Exact fp32 dist, BIT-IDENTICAL to R10's sequence:
          // quad-split partials by d%4, ascending d, (s0+s1)+(s2+s3),
          // dist = (z2 + e2[k]) - 2*dot.
          int code = t * 16 + c15;
          int row = rowbase + rt * 16 + g * 4 + r;
          const float4* zp = (const float4*)(z + (size_t)row * D);
          const float4* epv = (const float4*)(emb + (size_t)code * D);
          float s0 = 0.f, s1 = 0.f, s2 = 0.f, s3 = 0.f;
#pragma unroll 4
          for (int i = 0; i < 16; ++i) {
            float4 a = zp[i];
            float4 b = epv[i];
            s0 = fmaf(a.x, b.x, s0);
            s1 = fmaf(a.y, b.y, s1);
            s2 = fmaf(a.z, b.z, s2);
            s3 = fmaf(a.w, b.w, s3);
          }
          float dot = (s0 + s1) + (s2 + s3);
          float de = (z2r[rt][r] + e2v) - 2.0f * dot;
          unsigned long long pk =
              ((unsigned long long)__float_as_uint(de) << 32) | (unsigned)code;
          atomicMin(cand + row, pk);  // lexicographic (dist, idx): first-index ties
        }
      }
    }
    boff += 2048;
    e2p += 16;
  }
}

// Epilogue: read winner index, gather/losses/counts/index write (as before).
__global__ __launch_bounds__(256) void vq_epilogue(const float* __restrict__ z,
                                                   const float* __restrict__ emb,
                                                   const unsigned long long* __restrict__ cand,
                                                   float* __restrict__ out,
                                                   int* __restrict__ counts,
                                                   float* __restrict__ loss) {
  __shared__ float red[4];
  const int tid = threadIdx.x;
  const int n = blockIdx.x * 256 + tid;

  int bidx = (int)(unsigned)(cand[n] & 0xFFFFFFFFull);

  out[(size_t)N * D + 3 + n] = (float)bidx;
  atomicAdd(&counts[bidx], 1);

  const float4* zp = (const float4*)(z + (size_t)n * D);
  const float4* qp = (const float4*)(emb + (size_t)bidx * D);
  float4* op = (float4*)(out + (size_t)n * D);
  float lsum = 0.f;
#pragma unroll
  for (int i = 0; i < 16; ++i) {
    float4 q = qp[i];
    float4 zz = zp[i];
    float dx = q.x - zz.x, dy = q.y - zz.y, dz = q.z - zz.z, dw = q.w - zz.w;
    lsum = fmaf(dx, dx, lsum);
    lsum = fmaf(dy, dy, lsum);
    lsum = fmaf(dz, dz, lsum);
    lsum = fmaf(dw, dw, lsum);
    // z_q_st = z + (z_q - z), replicated op-for-op
    float4 r;
    r.x = zz.x + dx; r.y = zz.y + dy; r.z = zz.z + dz; r.w = zz.w + dw;
    op[i] = r;
  }

#pragma unroll
  for (int off = 32; off > 0; off >>= 1) lsum += __shfl_down(lsum, off);
  if ((tid & 63) == 0) red[tid >> 6] = lsum;
  __syncthreads();
  if (tid == 0) atomicAdd(loss, (red[0] + red[1]) + (red[2] + red[3]));
}

__global__ __launch_bounds__(256) void finalize_kernel(const int* __restrict__ counts,
                                                       const float* __restrict__ loss,
                                                       float* __restrict__ out) {
  const int tid = threadIdx.x;
  double ent = 0.0;
  int active = 0;
  for (int k = tid; k < K; k += 256) {
    int c = counts[k];
    float p = (float)c / 65536.0f;
    if (c > 0) active++;
    ent += (double)(p * logf(p + 1e-10f));
  }
#pragma unroll
  for (int off = 32; off > 0; off >>= 1) {
    ent += __shfl_down(ent, off);
    active += __shfl_down(active, off);
  }
  __shared__ double ered[4];
  __shared__ int ared[4];
  if ((tid & 63) == 0) { ered[tid >> 6] = ent; ared[tid >> 6] = active; }
  __syncthreads();
  if (tid == 0) {
    double e = (ered[0] + ered[1]) + (ered[2] + ered[3]);
    int a = (ared[0] + ared[1]) + (ared[2] + ared[3]);
    float mean = *loss / (float)((size_t)N * D);
    float cb = mean;
    float cm = mean;
    float vq = cb + 0.25f * cm;
    size_t base = (size_t)N * D;
    out[base + 0] = vq;
    out[base + 1] = cb;
    out[base + 2] = cm;
    out[base + 3 + N] = (float)exp(-e);
    out[base + 4 + N] = (float)a;
  }
}

extern "C" void kernel_launch(void* const* d_in, const int* in_sizes, int n_in,
                              void* d_out, int out_size, void* d_ws, size_t ws_size,
                              hipStream_t stream) {
  const float* z = (const float*)d_in[0];
  const float* emb = (const float*)d_in[1];
  float* out = (float*)d_out;

  char* w = (char*)d_ws;
  float* e2 = (float*)w;                          w += (size_t)K * sizeof(float);
  int* counts = (int*)w;                          w += (size_t)K * sizeof(int);
  float* loss = (float*)w;                        w += 256;  // keep alignment
  float* z2 = (float*)w;                          w += (size_t)N * sizeof(float);
  float* amin = (float*)w;                        w += (size_t)N * sizeof(float);
  unsigned long long* cand = (unsigned long long*)w;
                                                  w += (size_t)N * sizeof(unsigned long long);
  unsigned short* eh = (unsigned short*)w;        w += (size_t)K * D * sizeof(unsigned short);
  unsigned short* el = (unsigned short*)w;

  prep_emb<<<K / 256, 256, 0, stream>>>(emb, e2, counts, loss, eh, el);
  prep_z<<<N / 256, 256, 0, stream>>>(z, z2, cand);
  sweep1<<<N / 128, 256, 0, stream>>>(z, z2, e2, eh, el, amin);
  sweep2<<<N / 128, 256, 0, stream>>>(z, emb, z2, e2, eh, el, amin, cand);
  vq_epilogue<<<N / 256, 256, 0, stream>>>(z, emb, cand, out, counts, loss);
  finalize_kernel<<<1, 256, 0, stream>>>(counts, loss, out);
}